// Round 6
// baseline (123.968 us; speedup 1.0000x reference)
//
#include <hip/hip_runtime.h>
#include <math.h>

#define N_G 512
#define IMG_H 324
#define IMG_W 332
#define N_C 120
#define HW (IMG_H*IMG_W)
#define CHUNK 64
#define TSX 21                 // tiles in x (16 px)
#define TSY 81                 // tiles in y (4 px)
#define NT (TSX*TSY)

// One 512-thread block (8 waves) per 16x4 tile. All waves' lanes map to the
// same 64 pixels; waves split the 120 channels (4 interleaved float4 groups
// each: c = 4w + 32k). Per chunk of 64 hits:
//   A: alpha computed ONCE (split over 8 waves) -> buf[j][px]; liveness ballot
//   B: each wave fused walk: a from buf (b32), its own T chain in registers
//      (identical across waves; dead hits exact no-ops since 1-a==1.0f),
//      spec rows via broadcast dwordx4 from L2 (no staging), 12-16 FMA
// 2 barriers/chunk, no serial wave0 phase, no per-iteration break-ballot
// (early-stop decided once per chunk; T identical across waves -> uniform).
// Aggregate cost/hit ~= alpha x1 + (T+ovh) x8 + split-invariant FMA/loads:
// lower than r4 (alpha x4, 3 barriers, serial 1b) and r5 (alpha+T x16).

__global__ __launch_bounds__(512, 6) void k_render(
    const float* __restrict__ pos, const float* __restrict__ scales,
    const float* __restrict__ opac, const float* __restrict__ Km,
    const float* __restrict__ Em, const float* __restrict__ spec,
    const float* __restrict__ tm, float* __restrict__ out)
{
  __shared__ __align__(16) float prm[N_G*8];     // rank-sorted hit params (16 KB)
  __shared__ __align__(16) float buf[CHUNK*64];  // alpha[j][px] (16 KB)
  __shared__ __align__(16) float key[N_G+4];     // depth keys (2 KB)
  __shared__ unsigned long long livem[8];
  __shared__ int wcnt[8];
  // ~34.5 KB -> LDS allows 4 blocks/CU; launch_bounds caps at 3 (24 waves/CU)

  const int tid  = threadIdx.x;
  const int w    = tid >> 6;            // wave 0..7
  const int lane = tid & 63;
  const int tx = lane & 15, ty = lane >> 4;
  const unsigned long long ltm = (1ull << lane) - 1ull;

  // ---- prep: exactly one gaussian per thread (512 == N_G) ----
  float psx, psy, pc00, pc11, pl2, pdep;
  float bxmin, bxmax, bymin, bymax;
  {
    const float E0=Em[0],E1=Em[1],E2=Em[2],E3=Em[3],
                E4=Em[4],E5=Em[5],E6=Em[6],E7=Em[7],
                E8=Em[8],E9=Em[9],E10=Em[10],E11=Em[11];
    const float K0=Km[0],K1=Km[1],K2=Km[2],
                K3=Km[3],K4=Km[4],K5=Km[5],
                K6=Km[6],K7=Km[7],K8=Km[8];
    const int g = tid;                           // original index
    float p0 = pos[g*3+0], p1 = pos[g*3+1], p2 = pos[g*3+2];
    float cam0 = E0*p0 + E1*p1 + E2*p2  + E3;
    float cam1 = E4*p0 + E5*p1 + E6*p2  + E7;
    float cam2 = E8*p0 + E9*p1 + E10*p2 + E11;
    float pr0 = K0*cam0 + K1*cam1 + K2*cam2;
    float pr1 = K3*cam0 + K4*cam1 + K5*cam2;
    float pr2 = K6*cam0 + K7*cam1 + K8*cam2;
    float inv = 1.0f/(pr2 + 1e-6f);
    float sx = pr0*inv, sy = pr1*inv;
    float depth = cam2;
    bool valid = (depth > 0.01f) && (depth < 100.0f)
              && (sx > -100.0f) && (sx < (float)IMG_W + 100.0f)
              && (sy > -100.0f) && (sy < (float)IMG_H + 100.0f);
    bool off = (sx < -(float)IMG_W) || (sx > 2.0f*(float)IMG_W)
            || (sy < -(float)IMG_H) || (sy > 2.0f*(float)IMG_H);
    bool skip = off || (!valid);
    float s0 = scales[g*3+0], s1 = scales[g*3+1];
    float v0 = s0*s0 + 1e-4f, v1 = s1*s1 + 1e-4f;
    const float HL2E = 0.72134752f;              // 0.5*log2(e)
    psx = sx; psy = sy;
    pc00 = HL2E/v0; pc11 = HL2E/v1;
    pl2 = __log2f(skip ? 0.0f : opac[g]);        // op=0 -> -inf -> exp2 -> 0
    pdep = depth;
    float rx = 6.0f*sqrtf(v0);                   // mahal cutoff 36 (6 sigma)
    float ry = 6.0f*sqrtf(v1);
    bxmin = skip ?  1e9f : sx - rx;
    bxmax = skip ? -1e9f : sx + rx;
    bymin = skip ?  1e9f : sy - ry;
    bymax = skip ? -1e9f : sy + ry;
  }

  // center-out bijection: heavy central tiles get the lowest blockIdx
  const int t = blockIdx.x;
  const int jx = t % TSX, ky = t / TSX;
  const int bx = 10 + ((jx & 1) ? ((jx+1)>>1) : -((jx+1)>>1));
  const int by = 40 + ((ky & 1) ? ((ky+1)>>1) : -((ky+1)>>1));

  const int x = bx*16 + tx;
  const int y = by*4 + ty;
  const bool inb = (x < IMG_W) && (y < IMG_H);
  const float px = (float)min(x, IMG_W-1);
  const float py = (float)min(y, IMG_H-1);
  const float wxmin = (float)(bx*16), wxmax = wxmin + 15.0f;
  const float wymin = (float)(by*4),  wymax = wymin + 3.0f;

  // ---- build: ballot compaction + per-tile depth rank-sort ----
  bool hit = !(bxmin > wxmax || bxmax < wxmin ||
               bymin > wymax || bymax < wymin);
  unsigned long long m = __ballot(hit);
  if (lane == 0) wcnt[w] = __popcll(m);
  __syncthreads();
  int offw = 0;
  #pragma unroll
  for (int k = 0; k < 8; ++k) if (k < w) offw += wcnt[k];
  int nh = 0;
  #pragma unroll
  for (int k = 0; k < 8; ++k) nh += wcnt[k];
  // compacted position (compaction order == original-index order)
  const int p = offw + __popcll(m & ltm);
  if (hit) key[p] = pdep;
  if (tid < 4) key[nh + tid] = 1e30f;            // pad for float4 scan
  __syncthreads();

  // rank-scan (broadcast b128 reads); stable tie-break by compacted position
  if (hit) {
    int r = 0;
    const float d = pdep;
    for (int j = 0; j < nh; j += 4) {
      float4 k4 = *(const float4*)&key[j];
      r += (k4.x < d || (k4.x == d && j+0 < p)) ? 1 : 0;
      r += (k4.y < d || (k4.y == d && j+1 < p)) ? 1 : 0;
      r += (k4.z < d || (k4.z == d && j+2 < p)) ? 1 : 0;
      r += (k4.w < d || (k4.w == d && j+3 < p)) ? 1 : 0;
    }
    *(float4*)&prm[r*8]   = make_float4(psx, psy, pc00, pc11);
    *(float4*)&prm[r*8+4] = make_float4(pl2, pdep,
                               __int_as_float(tid*N_C), 0.0f);
  }
  __syncthreads();

  // ---- main: 2 barriers per 64-hit chunk ----
  float T = 1.0f, dacc = 0.0f;          // T identical across all 8 waves
  float4 acc0={0,0,0,0}, acc1={0,0,0,0}, acc2={0,0,0,0}, acc3={0,0,0,0};
  const int gch = 4*w;                  // base channel; groups at +0,+32,+64,+96
  const bool g3ok = (w < 6);            // 4w+96 < 120

  for (int cb = 0; cb < nh; cb += CHUNK) {
    const int nc = min(CHUNK, nh - cb);

    // phase A: alpha once per tile (split over 8 waves) + liveness
    unsigned long long lm = 0;
    #pragma unroll 2
    for (int j = w; j < nc; j += 8) {
      float4 q0 = *(const float4*)&prm[(cb+j)*8];     // uniform b128
      float l2op = prm[(cb+j)*8+4];
      float dx = px - q0.x, dy = py - q0.y;
      float e = l2op - (q0.z*dx*dx + q0.w*dy*dy);     // log2(alpha)
      buf[j*64 + lane] = exp2f(e);
      if (__ballot(e > -30.0f)) lm |= 1ull << j;      // else 1-a==1.0f exactly
    }
    if (lane == 0) livem[w] = lm;
    __syncthreads();
    unsigned long long mm = livem[0]|livem[1]|livem[2]|livem[3]
                           |livem[4]|livem[5]|livem[6]|livem[7];

    // phase B: per-wave fused T-chain + channel accumulation (no sync inside)
    #pragma unroll 2
    for (int j = 0; mm; ++j, mm >>= 1) {
      if (!(mm & 1ull)) continue;
      float a = buf[j*64 + lane];                     // conflict-free b32
      float4 q1 = *(const float4*)&prm[(cb+j)*8+4];   // uniform b128
      float wv = a * T;
      T *= (1.0f - a);
      if (w == 0) dacc = fmaf(q1.y, wv, dacc);
      const float* sp = spec + __float_as_int(q1.z) + gch;  // broadcast L2
      float4 s0 = *(const float4*)(sp);
      float4 s1 = *(const float4*)(sp + 32);
      float4 s2 = *(const float4*)(sp + 64);
      acc0.x = fmaf(wv, s0.x, acc0.x);
      acc0.y = fmaf(wv, s0.y, acc0.y);
      acc0.z = fmaf(wv, s0.z, acc0.z);
      acc0.w = fmaf(wv, s0.w, acc0.w);
      acc1.x = fmaf(wv, s1.x, acc1.x);
      acc1.y = fmaf(wv, s1.y, acc1.y);
      acc1.z = fmaf(wv, s1.z, acc1.z);
      acc1.w = fmaf(wv, s1.w, acc1.w);
      acc2.x = fmaf(wv, s2.x, acc2.x);
      acc2.y = fmaf(wv, s2.y, acc2.y);
      acc2.z = fmaf(wv, s2.z, acc2.z);
      acc2.w = fmaf(wv, s2.w, acc2.w);
      if (g3ok) {
        float4 s3 = *(const float4*)(sp + 96);
        acc3.x = fmaf(wv, s3.x, acc3.x);
        acc3.y = fmaf(wv, s3.y, acc3.y);
        acc3.z = fmaf(wv, s3.z, acc3.z);
        acc3.w = fmaf(wv, s3.w, acc3.w);
      }
    }
    __syncthreads();   // buf reused next chunk
    // early stop: T bitwise-identical across waves -> uniform branch (safe)
    if (!__ballot(T >= 1e-5f)) break;  // front-to-back: remainder <= T
  }

  // ---- epilogue: store wave-exclusive channel groups (no combine) ----
  if (inb) {
    const int pixi = y*IMG_W + x;
    const float bgT = T;                // BG*(1 - A_final), BG = 1.0
    #pragma unroll
    for (int k = 0; k < 4; ++k) {
      const int c = gch + 32*k;
      if (c < N_C) {
        float4 a4 = (k==0) ? acc0 : (k==1) ? acc1 : (k==2) ? acc2 : acc3;
        float4 t4 = *(const float4*)&tm[c];
        out[(c+0)*HW + pixi] = (a4.x + bgT)*t4.x;
        out[(c+1)*HW + pixi] = (a4.y + bgT)*t4.y;
        out[(c+2)*HW + pixi] = (a4.z + bgT)*t4.z;
        out[(c+3)*HW + pixi] = (a4.w + bgT)*t4.w;
      }
    }
    if (w == 0) out[N_C*HW + pixi] = dacc;           // depth image
    if (w == 1) out[N_C*HW + HW + pixi] = 1.0f - T;  // A_final
  }
}

extern "C" void kernel_launch(void* const* d_in, const int* in_sizes, int n_in,
                              void* d_out, int out_size, void* d_ws, size_t ws_size,
                              hipStream_t stream) {
  const float* pos    = (const float*)d_in[0];
  // d_in[1] rotations: unused by the reference
  const float* scales = (const float*)d_in[2];
  const float* opac   = (const float*)d_in[3];
  const float* spec   = (const float*)d_in[4];
  const float* tm     = (const float*)d_in[5];
  const float* K      = (const float*)d_in[6];
  const float* E      = (const float*)d_in[7];
  float* out = (float*)d_out;
  (void)d_ws; (void)ws_size;   // no workspace needed

  k_render<<<NT, 512, 0, stream>>>(pos, scales, opac, K, E, spec, tm, out);
}

// Round 7
// 111.693 us; speedup vs baseline: 1.1099x; 1.1099x over previous
//
#include <hip/hip_runtime.h>
#include <math.h>

#define N_G 512
#define IMG_H 324
#define IMG_W 332
#define N_C 120
#define HW (IMG_H*IMG_W)
#define CHUNK 48               // <=64 (ull liveness bitmask); 4 blocks/CU
#define TSX 21                 // tiles in x (16 px)
#define TSY 81                 // tiles in y (4 px)
#define NT (TSX*TSY)
#define NBLK (NT*4)            // 4 channel-split blocks per tile

// 4 blocks per 16x4 tile; block cq owns interleaved float4 channel groups
//   g = cq + 8w (+4): disjoint outputs, no cross-block combine.  (= round-4
// structure, which measured fastest: k_render ~25us, total 113.7us.)
// Change vs round 4: the wave0-SERIAL cumprod phase (1b) and its barrier are
// deleted. Each wave fuses the T-chain into its own accumulation walk:
// a comes from buf (phase A), wv = a*T, T *= (1-a) in registers. T is
// bitwise-identical across waves (same pixel mapping, same buf values, same
// walk order), so the chunk-end early-stop ballot is wave-uniform and safe.
// 2 barriers/chunk instead of 3; no serial phase on the critical path.

__global__ __launch_bounds__(256, 4) void k_render(
    const float* __restrict__ pos, const float* __restrict__ scales,
    const float* __restrict__ opac, const float* __restrict__ Km,
    const float* __restrict__ Em, const float* __restrict__ spec,
    const float* __restrict__ tm, float* __restrict__ out)
{
  __shared__ __align__(16) float prm[N_G*8];     // rank-sorted hit params (16 KB)
  __shared__ __align__(16) float buf[CHUNK*64];  // keys during build; alpha (12 KB)
  __shared__ __align__(16) float sbuf[CHUNK*32]; // staged 30-ch rows (6 KB)
  __shared__ unsigned long long livem[4];
  __shared__ int wcnt[4];
  // total ~35 KB -> 4 blocks/CU (16 waves/CU)

  const int tid  = threadIdx.x;
  const int w    = tid >> 6;
  const int lane = tid & 63;
  const int tx = lane & 15, ty = lane >> 4;
  const unsigned long long ltm = (1ull << lane) - 1ull;

  const int t  = blockIdx.x >> 2;       // tile
  const int cq = blockIdx.x & 3;        // channel quarter

  // ---- prep: project 2 gaussians per thread into registers ----
  float psx[2], psy[2], pc00[2], pc11[2], pl2[2], pd[2];
  float bxmin[2], bxmax[2], bymin[2], bymax[2];
  {
    const float E0=Em[0],E1=Em[1],E2=Em[2],E3=Em[3],
                E4=Em[4],E5=Em[5],E6=Em[6],E7=Em[7],
                E8=Em[8],E9=Em[9],E10=Em[10],E11=Em[11];
    const float K0=Km[0],K1=Km[1],K2=Km[2],
                K3=Km[3],K4=Km[4],K5=Km[5],
                K6=Km[6],K7=Km[7],K8=Km[8];
    #pragma unroll
    for (int q = 0; q < 2; ++q) {
      const int g = w*128 + lane + q*64;           // original index (wave-major)
      float p0 = pos[g*3+0], p1 = pos[g*3+1], p2 = pos[g*3+2];
      float cam0 = E0*p0 + E1*p1 + E2*p2  + E3;
      float cam1 = E4*p0 + E5*p1 + E6*p2  + E7;
      float cam2 = E8*p0 + E9*p1 + E10*p2 + E11;
      float pr0 = K0*cam0 + K1*cam1 + K2*cam2;
      float pr1 = K3*cam0 + K4*cam1 + K5*cam2;
      float pr2 = K6*cam0 + K7*cam1 + K8*cam2;
      float inv = 1.0f/(pr2 + 1e-6f);
      float sx = pr0*inv, sy = pr1*inv;
      float depth = cam2;
      bool valid = (depth > 0.01f) && (depth < 100.0f)
                && (sx > -100.0f) && (sx < (float)IMG_W + 100.0f)
                && (sy > -100.0f) && (sy < (float)IMG_H + 100.0f);
      bool off = (sx < -(float)IMG_W) || (sx > 2.0f*(float)IMG_W)
              || (sy < -(float)IMG_H) || (sy > 2.0f*(float)IMG_H);
      bool skip = off || (!valid);
      float s0 = scales[g*3+0], s1 = scales[g*3+1];
      float v0 = s0*s0 + 1e-4f, v1 = s1*s1 + 1e-4f;
      const float HL2E = 0.72134752f;              // 0.5*log2(e)
      psx[q] = sx; psy[q] = sy;
      pc00[q] = HL2E/v0; pc11[q] = HL2E/v1;
      pl2[q] = __log2f(skip ? 0.0f : opac[g]);     // op=0 -> -inf -> exp2 -> 0
      pd[q]  = depth;
      float rx = 6.0f*sqrtf(v0);                   // mahal cutoff 36 (6 sigma)
      float ry = 6.0f*sqrtf(v1);
      bxmin[q] = skip ?  1e9f : sx - rx;
      bxmax[q] = skip ? -1e9f : sx + rx;
      bymin[q] = skip ?  1e9f : sy - ry;
      bymax[q] = skip ? -1e9f : sy + ry;
    }
  }

  // center-out bijection: heavy central tiles get the lowest blockIdx
  const int jx = t % TSX, ky = t / TSX;
  const int bx = 10 + ((jx & 1) ? ((jx+1)>>1) : -((jx+1)>>1));
  const int by = 40 + ((ky & 1) ? ((ky+1)>>1) : -((ky+1)>>1));

  const int x = bx*16 + tx;
  const int y = by*4 + ty;
  const bool inb = (x < IMG_W) && (y < IMG_H);
  const float px = (float)min(x, IMG_W-1);
  const float py = (float)min(y, IMG_H-1);
  const float wxmin = (float)(bx*16), wxmax = wxmin + 15.0f;
  const float wymin = (float)(by*4),  wymax = wymin + 3.0f;

  // ---- build: ballot compaction + per-tile depth rank-sort ----
  bool h0 = !(bxmin[0] > wxmax || bxmax[0] < wxmin ||
              bymin[0] > wymax || bymax[0] < wymin);
  bool h1 = !(bxmin[1] > wxmax || bxmax[1] < wxmin ||
              bymin[1] > wymax || bymax[1] < wymin);
  unsigned long long m0 = __ballot(h0), m1 = __ballot(h1);
  int c0 = __popcll(m0);
  if (lane == 0) wcnt[w] = c0 + __popcll(m1);
  __syncthreads();
  int offw = 0;
  #pragma unroll
  for (int k = 0; k < 4; ++k) if (k < w) offw += wcnt[k];
  const int nh = wcnt[0] + wcnt[1] + wcnt[2] + wcnt[3];
  // compacted depth keys (compaction order == original-index order)
  const int p0 = offw + __popcll(m0 & ltm);
  const int p1 = offw + c0 + __popcll(m1 & ltm);
  if (h0) buf[p0] = pd[0];
  if (h1) buf[p1] = pd[1];
  if (tid < 4) buf[nh + tid] = 1e30f;            // pad for float4 scan
  __syncthreads();

  // rank-scan (broadcast b128 reads); stable tie-break by compacted position
  if (h0 | h1) {
    int r0 = 0, r1 = 0;
    const float d0 = pd[0], d1 = pd[1];
    for (int j = 0; j < nh; j += 4) {
      float4 k4 = *(const float4*)&buf[j];
      if (h0) {
        r0 += (k4.x < d0 || (k4.x == d0 && j+0 < p0)) ? 1 : 0;
        r0 += (k4.y < d0 || (k4.y == d0 && j+1 < p0)) ? 1 : 0;
        r0 += (k4.z < d0 || (k4.z == d0 && j+2 < p0)) ? 1 : 0;
        r0 += (k4.w < d0 || (k4.w == d0 && j+3 < p0)) ? 1 : 0;
      }
      if (h1) {
        r1 += (k4.x < d1 || (k4.x == d1 && j+0 < p1)) ? 1 : 0;
        r1 += (k4.y < d1 || (k4.y == d1 && j+1 < p1)) ? 1 : 0;
        r1 += (k4.z < d1 || (k4.z == d1 && j+2 < p1)) ? 1 : 0;
        r1 += (k4.w < d1 || (k4.w == d1 && j+3 < p1)) ? 1 : 0;
      }
    }
    if (h0) {
      *(float4*)&prm[r0*8]   = make_float4(psx[0], psy[0], pc00[0], pc11[0]);
      *(float4*)&prm[r0*8+4] = make_float4(pl2[0], pd[0],
                                 __int_as_float((w*128 + lane)*N_C), 0.0f);
    }
    if (h1) {
      *(float4*)&prm[r1*8]   = make_float4(psx[1], psy[1], pc00[1], pc11[1]);
      *(float4*)&prm[r1*8+4] = make_float4(pl2[1], pd[1],
                                 __int_as_float((w*128 + lane + 64)*N_C), 0.0f);
    }
  }
  __syncthreads();

  float T = 1.0f, dacc = 0.0f;          // T bitwise-identical across waves
  float4 acc0 = {0,0,0,0}, acc1 = {0,0,0,0};   // groups g0 = cq+8w, g1 = g0+4
  const int g0 = cq + 8*w;
  const bool g1ok = (g0 + 4) < 30;
  // staging channel for lanes < 32: c = 16*(lane>>2) + 4*cq + (lane&3)
  const int stc = 16*(lane >> 2) + 4*cq + (lane & 3);
  const bool stok = (lane < 32) && (stc < N_C);

  for (int cb = 0; cb < nh; cb += CHUNK) {
    const int nc = min(CHUNK, nh - cb);

    // ---- phase A: alpha + liveness ballot + 30-ch staging (live rows) ----
    unsigned long long lm = 0;
    #pragma unroll 2
    for (int j = w; j < nc; j += 4) {
      float4 q0 = *(const float4*)&prm[(cb+j)*8];     // ds_read_b128
      float4 q1 = *(const float4*)&prm[(cb+j)*8+4];
      float dx = px - q0.x, dy = py - q0.y;
      float m = q0.z*dx*dx + q0.w*dy*dy;              // log2-units
      float e = q1.x - m;
      buf[j*64 + lane] = exp2f(e);                    // raw alpha
      unsigned long long bl = __ballot(e > -24.0f);   // alpha >= ~6e-8 anywhere?
      if (bl) {
        lm |= 1ull << j;
        int sbase = __float_as_int(q1.z);             // src*120
        if (stok) sbuf[j*32 + lane] = spec[sbase + stc];
      }
    }
    if (lane == 0) livem[w] = lm;
    __syncthreads();
    const unsigned long long mask = livem[0]|livem[1]|livem[2]|livem[3];

    // ---- phase B: per-wave fused T-chain + channel accumulation ----
    unsigned long long m2 = mask;
    while (m2) {
      const int j = __builtin_ctzll(m2); m2 &= m2 - 1;
      float a  = buf[j*64 + lane];                    // conflict-free b32
      float wv = a * T;
      T *= (1.0f - a);
      if (w == 0)                                     // wave-uniform branch
        dacc = fmaf(prm[(cb+j)*8+5], wv, dacc);       // depth (used by cq2)
      const float* row = &sbuf[j*32 + 8*w];           // uniform b128 reads
      float4 s0 = *(const float4*)(row);
      acc0.x = fmaf(wv, s0.x, acc0.x);
      acc0.y = fmaf(wv, s0.y, acc0.y);
      acc0.z = fmaf(wv, s0.z, acc0.z);
      acc0.w = fmaf(wv, s0.w, acc0.w);
      if (g1ok) {
        float4 s1 = *(const float4*)(row + 4);
        acc1.x = fmaf(wv, s1.x, acc1.x);
        acc1.y = fmaf(wv, s1.y, acc1.y);
        acc1.z = fmaf(wv, s1.z, acc1.z);
        acc1.w = fmaf(wv, s1.w, acc1.w);
      }
    }
    __syncthreads();   // buf/sbuf reused next chunk
    // early stop: T bitwise-identical across waves -> uniform branch (safe)
    if (!__ballot(T >= 1e-5f)) break;  // front-to-back: remainder <= T
  }

  // ---- epilogue: store wave-exclusive channel groups (no combine) ----
  if (inb) {
    const int pixi = y*IMG_W + x;
    const float bgT = T;                // BG*(1 - A_final), BG = 1.0
    float4 t0 = *(const float4*)&tm[4*g0];
    out[(4*g0+0)*HW + pixi] = (acc0.x + bgT)*t0.x;
    out[(4*g0+1)*HW + pixi] = (acc0.y + bgT)*t0.y;
    out[(4*g0+2)*HW + pixi] = (acc0.z + bgT)*t0.z;
    out[(4*g0+3)*HW + pixi] = (acc0.w + bgT)*t0.w;
    if (g1ok) {
      const int g1 = g0 + 4;
      float4 t1 = *(const float4*)&tm[4*g1];
      out[(4*g1+0)*HW + pixi] = (acc1.x + bgT)*t1.x;
      out[(4*g1+1)*HW + pixi] = (acc1.y + bgT)*t1.y;
      out[(4*g1+2)*HW + pixi] = (acc1.z + bgT)*t1.z;
      out[(4*g1+3)*HW + pixi] = (acc1.w + bgT)*t1.w;
    }
    if (cq == 2 && w == 0) out[N_C*HW + pixi] = dacc;          // depth
    if (cq == 3 && w == 0) out[N_C*HW + HW + pixi] = 1.0f - T; // A_final
  }
}

extern "C" void kernel_launch(void* const* d_in, const int* in_sizes, int n_in,
                              void* d_out, int out_size, void* d_ws, size_t ws_size,
                              hipStream_t stream) {
  const float* pos    = (const float*)d_in[0];
  // d_in[1] rotations: unused by the reference
  const float* scales = (const float*)d_in[2];
  const float* opac   = (const float*)d_in[3];
  const float* spec   = (const float*)d_in[4];
  const float* tm     = (const float*)d_in[5];
  const float* K      = (const float*)d_in[6];
  const float* E      = (const float*)d_in[7];
  float* out = (float*)d_out;
  (void)d_ws; (void)ws_size;   // no workspace needed

  k_render<<<NBLK, 256, 0, stream>>>(pos, scales, opac, K, E, spec, tm, out);
}